// Round 1
// 968.984 us; speedup vs baseline: 1.0850x; 1.0850x over previous
//
#include <hip/hip_runtime.h>
#include <stdint.h>

typedef unsigned short u16;
using frag8 = __attribute__((ext_vector_type(8))) short;
using f32x4 = __attribute__((ext_vector_type(4))) float;

#define NTOK 32768
#define FDIM 512

__device__ __forceinline__ float bflo(uint32_t p){ union{uint32_t u; float f;} v; v.u = p<<16; return v.f; }
__device__ __forceinline__ float bfhi(uint32_t p){ union{uint32_t u; float f;} v; v.u = p & 0xffff0000u; return v.f; }
__device__ __forceinline__ float bf1(u16 x){ union{uint32_t u; float f;} v; v.u = ((uint32_t)x)<<16; return v.f; }
__device__ __forceinline__ u16 f2bf(float f){
  union{float f; uint32_t u;} v; v.f = f;
  uint32_t u = v.u;
  u += 0x7fffu + ((u>>16)&1u);   // round-to-nearest-even
  return (u16)(u>>16);
}

__device__ __forceinline__ void async16(const void* g, void* l){
  __builtin_amdgcn_global_load_lds((const __attribute__((address_space(1))) uint32_t*)g,
                                   (__attribute__((address_space(3))) uint32_t*)l, 16, 0, 0);
}

// -------------------- embedding + positional encoding (bf16 x only) --------------------
__global__ __launch_bounds__(256) void embed_kernel(const int* __restrict__ text,
    const float* __restrict__ emb, const float* __restrict__ pe,
    u16* __restrict__ xb, const int tok0){
  const int gid = blockIdx.x*256 + threadIdx.x;
  const int base = gid*4;
  const int tl = base >> 9;
  const int f  = base & 511;
  const int tg = tl + tok0;
  const int s  = tg & 511;
  const int tok = text[tg];
  const float4 e4 = *(const float4*)(emb + (size_t)tok*FDIM + f);
  const float4 p4 = *(const float4*)(pe  + (size_t)s*FDIM + f);
  ushort4 ob;
  ob.x = f2bf(e4.x + p4.x);
  ob.y = f2bf(e4.y + p4.y);
  ob.z = f2bf(e4.z + p4.z);
  ob.w = f2bf(e4.w + p4.w);
  *(ushort4*)(xb + base) = ob;
}

// -------------------- weight transpose + fp32->bf16: WT[lay][n][k], n: Wq|Wk|Wv|Wf --------------------
__global__ __launch_bounds__(256) void transpose_w(const float* __restrict__ Wq,
    const float* __restrict__ Wk, const float* __restrict__ Wv, const float* __restrict__ Wf,
    u16* __restrict__ WT){
  const int gid = blockIdx.x*256 + threadIdx.x;
  const int n   = gid & 2047;
  const int k8  = (gid>>11) & 63;
  const int lay = gid >> 17;
  const float* src; int col;
  if      (n <  512){ src = Wq; col = n;      }
  else if (n < 1024){ src = Wk; col = n-512;  }
  else if (n < 1536){ src = Wv; col = n-1024; }
  else              { src = Wf; col = n-1536; }
  src += (size_t)lay*FDIM*FDIM;
  u16 vals[8] __attribute__((aligned(16)));
  #pragma unroll
  for (int i=0;i<8;i++) vals[i] = f2bf(src[(size_t)(k8*8+i)*FDIM + col]);
  *(int4*)(WT + ((size_t)lay*2048 + n)*FDIM + k8*8) = *(const int4*)vals;
}

// -------------------- 256x256 ring-4 pipelined MFMA GEMM (BK=32, 8 waves) --------------------
// C = A[Mx512] * BT^T + bias (+bf16 residual in MODE 1).
// LDS: 4 slots x (256x32) for A and B = 128 KiB. While computing K-tile t (slot t&3),
// tile t+3 is staged into slot (t+3)&3 == slot of tile t-1, whose last ds_read completed
// before the barrier that opened tile t => stage writes land after old reads (race-free).
// One raw s_barrier + one counted vmcnt per tile; 8 loads (2 tiles) stay in flight (T3+T4).
// LDS read swizzle: chunk' = quad ^ ((lm>>1)&3); since global_load_lds writes linearly, the
// GLOBAL source address carries the same involution (rule #21: both sides or neither).
template<int MODE>
__global__ __launch_bounds__(512, 2) void gemm256(
    const u16* __restrict__ A, const u16* __restrict__ BT,
    const float* __restrict__ b0, const float* __restrict__ b1, const float* __restrict__ b2,
    const u16* __restrict__ resid, u16* __restrict__ C, const int ldC, const int NB){
  __shared__ __attribute__((aligned(16))) short As[4*256*32];   // 64 KiB
  __shared__ __attribute__((aligned(16))) short Bs[4*256*32];   // 64 KiB
  // T1: bijective XCD swizzle (grids here are multiples of 8)
  const int nwg = gridDim.x;
  const int orig = blockIdx.x;
  const int wg = ((nwg & 7) == 0) ? ((orig & 7)*(nwg >> 3) + (orig >> 3)) : orig;
  const int nblk = wg % NB, mblk = wg / NB;
  const int m0 = mblk << 8, n0 = nblk << 8;
  const int tid = threadIdx.x;
  const int wid = tid >> 6, l = tid & 63;
  const int lm = l & 15, quad = l >> 4;

  // ---- stage source: pre-swizzled per-lane global address; LDS dest stays linear ----
  // lane lands at LDS row (rnd*128 + wid*16 + l/4), chunk16 (l&3); wanted global chunk =
  // (l&3) ^ ((row>>1)&3) = (l&3) ^ ((l>>3)&3)  (rnd*128, wid*16 are 0 mod 4 after >>1).
  const int srow = wid*16 + (l >> 2);
  const int sch  = (l & 3) ^ ((l >> 3) & 3);
  const char* Asrc0 = (const char*)A  + ((size_t)(m0 + srow))*1024 + sch*16;
  const char* Asrc1 = Asrc0 + 128*1024;
  const char* Bsrc0 = (const char*)BT + ((size_t)(n0 + srow))*1024 + sch*16;
  const char* Bsrc1 = Bsrc0 + 128*1024;
  char* ldsAw = (char*)As + wid*1024;      // wave-uniform; HW adds lane*16
  char* ldsBw = (char*)Bs + wid*1024;

  f32x4 acc[8][4];
  #pragma unroll
  for (int i=0;i<8;i++)
    #pragma unroll
    for (int j=0;j<4;j++){ f32x4 z = {0.f,0.f,0.f,0.f}; acc[i][j] = z; }

  // ---- swizzled fragment-read bases (row base ≡ 0 mod 16 => sel depends on lm only) ----
  const int rsel = quad ^ ((lm >> 1) & 3);
  const int aB = ((wid>>2)*128 + lm)*32 + rsel*8;   // shorts within slot
  const int bB = ((wid&3)*64  + lm)*32 + rsel*8;

  // ---- prologue: stage tiles 0,1,2 (12 loads/thread) ----
  #pragma unroll
  for (int kt=0; kt<3; kt++){
    async16(Asrc0 + kt*64, ldsAw + kt*16384);
    async16(Asrc1 + kt*64, ldsAw + kt*16384 + 8192);
    async16(Bsrc0 + kt*64, ldsBw + kt*16384);
    async16(Bsrc1 + kt*64, ldsBw + kt*16384 + 8192);
  }

  for (int t=0; t<16; ++t){
    // tile t's 4 loads are older than the (<=8) loads of tiles t+1,t+2 -> counted wait
    if (t < 14)       asm volatile("s_waitcnt vmcnt(8)" ::: "memory");
    else if (t == 14) asm volatile("s_waitcnt vmcnt(4)" ::: "memory");
    else              asm volatile("s_waitcnt vmcnt(0)" ::: "memory");
    __builtin_amdgcn_s_barrier();
    asm volatile("" ::: "memory");
    const int slot = t & 3;
    const short* sA = As + slot*8192;
    const short* sB = Bs + slot*8192;
    frag8 af[4], bf[4], ag[4];
    #pragma unroll
    for (int mi=0; mi<4; mi++) af[mi] = *(const frag8*)(sA + aB + mi*512);
    #pragma unroll
    for (int nj=0; nj<4; nj++) bf[nj] = *(const frag8*)(sB + bB + nj*512);
    if (t < 13){
      const int s3 = (t+3) & 3, off = (t+3)*64;
      async16(Asrc0 + off, ldsAw + s3*16384);
      async16(Asrc1 + off, ldsAw + s3*16384 + 8192);
    }
    __builtin_amdgcn_s_setprio(1);
    #pragma unroll
    for (int mi=0; mi<4; mi++)
      #pragma unroll
      for (int nj=0; nj<4; nj++)
        acc[mi][nj] = __builtin_amdgcn_mfma_f32_16x16x32_bf16(af[mi], bf[nj], acc[mi][nj], 0,0,0);
    __builtin_amdgcn_s_setprio(0);
    #pragma unroll
    for (int mi=0; mi<4; mi++) ag[mi] = *(const frag8*)(sA + aB + 2048 + mi*512);
    if (t < 13){
      const int s3 = (t+3) & 3, off = (t+3)*64;
      async16(Bsrc0 + off, ldsBw + s3*16384);
      async16(Bsrc1 + off, ldsBw + s3*16384 + 8192);
    }
    __builtin_amdgcn_s_setprio(1);
    #pragma unroll
    for (int mi=0; mi<4; mi++)
      #pragma unroll
      for (int nj=0; nj<4; nj++)
        acc[4+mi][nj] = __builtin_amdgcn_mfma_f32_16x16x32_bf16(ag[mi], bf[nj], acc[4+mi][nj], 0,0,0);
    __builtin_amdgcn_s_setprio(0);
  }

  // ---- epilogue: bias (+residual) + bf16 store ----
  float bias[4]; int cols[4];
  #pragma unroll
  for (int nj=0;nj<4;nj++){
    const int c = n0 + (wid&3)*64 + nj*16 + lm;
    cols[nj] = c;
    if (MODE==0) bias[nj] = (c<512 ? b0[c] : (c<1024 ? b1[c-512] : b2[c-1024]));
    else         bias[nj] = b0[c];
  }
  #pragma unroll
  for (int mi=0; mi<8; mi++){
    const int rbase = m0 + (wid>>2)*128 + mi*16 + quad*4;
    #pragma unroll
    for (int r=0;r<4;r++){
      const size_t row = (size_t)(rbase + r);
      #pragma unroll
      for (int nj=0;nj<4;nj++){
        float v = acc[mi][nj][r] + bias[nj];
        if (MODE==1) v += bf1(resid[row*FDIM + cols[nj]]);
        C[row*(size_t)ldC + cols[nj]] = f2bf(v);
      }
    }
  }
}

// -------------------- per-token head-attention + residual(bf16) + LN1 (1 wave = 1 token) --------------------
__global__ __launch_bounds__(256) void attn_ln1(const u16* __restrict__ qkvb,
    const u16* __restrict__ xb, const float* __restrict__ gam, const float* __restrict__ bet,
    u16* __restrict__ y1b){
  __shared__ __attribute__((aligned(16))) u16 sQ[4][1536];
  __shared__ float sWt[4][64];
  const int tid = threadIdx.x, w = tid>>6, l = tid&63;
  const int t = blockIdx.x*4 + w;
  {
    const int4* src = (const int4*)(qkvb + (size_t)t*1536);
    int4* dst = (int4*)(&sQ[w][0]);
    #pragma unroll
    for (int i=0;i<3;i++) dst[i*64 + l] = src[i*64 + l];
  }
  __syncthreads();
  const int h = l>>3, g = l&7;
  const u16* qrow = &sQ[w][h*64];
  const u16* krow = &sQ[w][512 + g*64];
  float sc = 0.f;
  const int dstart = (l&31)*2;
  #pragma unroll
  for (int i=0;i<32;i++){
    const int d = (dstart + 2*i) & 63;
    const uint32_t qp = *(const uint32_t*)(qrow + d);
    const uint32_t kp = *(const uint32_t*)(krow + d);
    sc += bflo(qp)*bflo(kp) + bfhi(qp)*bfhi(kp);
  }
  float mx = sc;
  mx = fmaxf(mx, __shfl_xor(mx,1));
  mx = fmaxf(mx, __shfl_xor(mx,2));
  mx = fmaxf(mx, __shfl_xor(mx,4));
  const float e = __expf(sc - mx);
  float ssum = e;
  ssum += __shfl_xor(ssum,1);
  ssum += __shfl_xor(ssum,2);
  ssum += __shfl_xor(ssum,4);
  sWt[w][l] = e / ssum;
  __syncthreads();
  float wt[8];
  #pragma unroll
  for (int gg=0;gg<8;gg++) wt[gg] = sWt[w][h*8+gg];
  float att[8] = {0,0,0,0,0,0,0,0};
  const int d0 = (l&7)*8;
  #pragma unroll
  for (int gg=0;gg<8;gg++){
    const int4 vv = *(const int4*)(&sQ[w][1024 + gg*64 + d0]);
    const uint32_t* vp = (const uint32_t*)&vv;
    #pragma unroll
    for (int p=0;p<4;p++){
      att[2*p]   += wt[gg]*bflo(vp[p]);
      att[2*p+1] += wt[gg]*bfhi(vp[p]);
    }
  }
  const size_t rb = (size_t)t*FDIM + l*8;
  const int4 xv = *(const int4*)(xb + rb);
  const uint32_t* xp = (const uint32_t*)&xv;
  float y[8]; float s1=0.f, s2=0.f;
  #pragma unroll
  for (int p=0;p<4;p++){
    y[2*p]   = att[2*p]   + bflo(xp[p]);
    y[2*p+1] = att[2*p+1] + bfhi(xp[p]);
  }
  #pragma unroll
  for (int j=0;j<8;j++){ s1 += y[j]; s2 += y[j]*y[j]; }
  #pragma unroll
  for (int off=1; off<64; off<<=1){ s1 += __shfl_xor(s1,off); s2 += __shfl_xor(s2,off); }
  const float mean = s1*(1.f/512.f);
  const float var  = s2*(1.f/512.f) - mean*mean;
  const float rstd = rsqrtf(var + 1e-5f);
  const float4 g0 = *(const float4*)(gam + l*8);
  const float4 g1v = *(const float4*)(gam + l*8 + 4);
  const float4 b0v = *(const float4*)(bet + l*8);
  const float4 b1v = *(const float4*)(bet + l*8 + 4);
  float of[8];
  of[0]=(y[0]-mean)*rstd*g0.x + b0v.x;
  of[1]=(y[1]-mean)*rstd*g0.y + b0v.y;
  of[2]=(y[2]-mean)*rstd*g0.z + b0v.z;
  of[3]=(y[3]-mean)*rstd*g0.w + b0v.w;
  of[4]=(y[4]-mean)*rstd*g1v.x + b1v.x;
  of[5]=(y[5]-mean)*rstd*g1v.y + b1v.y;
  of[6]=(y[6]-mean)*rstd*g1v.z + b1v.z;
  of[7]=(y[7]-mean)*rstd*g1v.w + b1v.w;
  u16 ob[8] __attribute__((aligned(16)));
  #pragma unroll
  for (int j=0;j<8;j++) ob[j] = f2bf(of[j]);
  *(int4*)(y1b + rb) = *(const int4*)ob;
}

// -------------------- LN2 over z (bf16); writes bf16 xb (next layer) or fp32 out --------------------
__global__ __launch_bounds__(256) void ln2_kernel(const u16* __restrict__ z,
    const float* __restrict__ gam, const float* __restrict__ bet,
    u16* __restrict__ xb, float* __restrict__ outp, const int final_){
  const int tid = threadIdx.x, w = tid>>6, l = tid&63;
  const int t = blockIdx.x*4 + w;
  const size_t rb = (size_t)t*FDIM + l*8;
  const int4 zv = *(const int4*)(z + rb);
  const uint32_t* zp = (const uint32_t*)&zv;
  float y[8];
  #pragma unroll
  for (int p=0;p<4;p++){ y[2*p]=bflo(zp[p]); y[2*p+1]=bfhi(zp[p]); }
  float s1=0.f, s2=0.f;
  #pragma unroll
  for (int j=0;j<8;j++){ s1+=y[j]; s2+=y[j]*y[j]; }
  #pragma unroll
  for (int off=1; off<64; off<<=1){ s1 += __shfl_xor(s1,off); s2 += __shfl_xor(s2,off); }
  const float mean = s1*(1.f/512.f);
  const float var  = s2*(1.f/512.f) - mean*mean;
  const float rstd = rsqrtf(var + 1e-5f);
  const float4 g0 = *(const float4*)(gam + l*8);
  const float4 g1v = *(const float4*)(gam + l*8 + 4);
  const float4 b0v = *(const float4*)(bet + l*8);
  const float4 b1v = *(const float4*)(bet + l*8 + 4);
  float of[8];
  of[0]=(y[0]-mean)*rstd*g0.x + b0v.x;
  of[1]=(y[1]-mean)*rstd*g0.y + b0v.y;
  of[2]=(y[2]-mean)*rstd*g0.z + b0v.z;
  of[3]=(y[3]-mean)*rstd*g0.w + b0v.w;
  of[4]=(y[4]-mean)*rstd*g1v.x + b1v.x;
  of[5]=(y[5]-mean)*rstd*g1v.y + b1v.y;
  of[6]=(y[6]-mean)*rstd*g1v.z + b1v.z;
  of[7]=(y[7]-mean)*rstd*g1v.w + b1v.w;
  if (final_){
    float4 o0; o0.x=of[0]; o0.y=of[1]; o0.z=of[2]; o0.w=of[3];
    float4 o1; o1.x=of[4]; o1.y=of[5]; o1.z=of[6]; o1.w=of[7];
    *(float4*)(outp + rb) = o0;
    *(float4*)(outp + rb + 4) = o1;
  } else {
    u16 ob[8] __attribute__((aligned(16)));
    #pragma unroll
    for (int j=0;j<8;j++) ob[j] = f2bf(of[j]);
    *(int4*)(xb + rb) = *(const int4*)ob;
  }
}

extern "C" void kernel_launch(void* const* d_in, const int* in_sizes, int n_in,
                              void* d_out, int out_size, void* d_ws, size_t ws_size,
                              hipStream_t stream){
  const int*   text = (const int*)d_in[0];
  const float* emb = (const float*)d_in[1];
  const float* pe  = (const float*)d_in[2];
  const float* Wq  = (const float*)d_in[3];
  const float* bq  = (const float*)d_in[4];
  const float* Wk  = (const float*)d_in[5];
  const float* bk  = (const float*)d_in[6];
  const float* Wv  = (const float*)d_in[7];
  const float* bv  = (const float*)d_in[8];
  const float* g1  = (const float*)d_in[9];
  const float* be1 = (const float*)d_in[10];
  const float* Wf  = (const float*)d_in[11];
  const float* bf_ = (const float*)d_in[12];
  const float* g2  = (const float*)d_in[13];
  const float* be2 = (const float*)d_in[14];
  float* outp = (float*)d_out;               // reference output dtype = float32

  // ---- layout: WT 12.6 MB + per-token {xb 1024 + y1b 1024 + qkv 3072} = 5120 B
  const size_t wtB = (size_t)6*2048*512*2;
  int T = NTOK;                               // single chunk if ws permits (~173 MB)
  while (T > 2048 && wtB + (size_t)T*5120 > ws_size) T >>= 1;

  char* ws = (char*)d_ws;
  u16*   WT  = (u16*)ws;
  char*  act = ws + wtB;
  u16*   xb  = (u16*)act;                       // T*1024 B
  u16*   y1b = (u16*)(act + (size_t)T*1024);    // T*1024 B
  u16*   qkv = (u16*)(act + (size_t)T*2048);    // T*3072 B
  u16*   zb  = qkv;                             // alias: qkv dead once attn_ln1 ran

  hipLaunchKernelGGL(transpose_w, dim3(3072), dim3(256), 0, stream, Wq, Wk, Wv, Wf, WT);

  const int chunks = NTOK / T;
  for (int c = 0; c < chunks; c++){
    const int tok0 = c*T;
    hipLaunchKernelGGL(embed_kernel, dim3(T/2), dim3(256), 0, stream, text, emb, pe, xb, tok0);
    for (int lay=0; lay<6; lay++){
      const u16* WTl = WT + (size_t)lay*2048*FDIM;
      hipLaunchKernelGGL((gemm256<0>), dim3((T/256)*6), dim3(512), 0, stream,
          xb, WTl, bq + lay*FDIM, bk + lay*FDIM, bv + lay*FDIM, (const u16*)nullptr, qkv, 1536, 6);
      hipLaunchKernelGGL(attn_ln1, dim3(T/4), dim3(256), 0, stream,
          qkv, xb, g1 + lay*FDIM, be1 + lay*FDIM, y1b);
      hipLaunchKernelGGL((gemm256<1>), dim3((T/256)*2), dim3(512), 0, stream,
          y1b, WTl + (size_t)1536*FDIM, bf_ + lay*FDIM, (const float*)nullptr, (const float*)nullptr,
          y1b, zb, 512, 2);
      hipLaunchKernelGGL(ln2_kernel, dim3(T/4), dim3(256), 0, stream,
          zb, g2 + lay*FDIM, be2 + lay*FDIM, xb, outp + (size_t)tok0*FDIM, (lay==5)?1:0);
    }
  }
}

// Round 2
// 916.348 us; speedup vs baseline: 1.1473x; 1.0574x over previous
//
#include <hip/hip_runtime.h>
#include <stdint.h>

typedef unsigned short u16;
using frag8 = __attribute__((ext_vector_type(8))) short;
using f32x4 = __attribute__((ext_vector_type(4))) float;

#define NTOK 32768
#define FDIM 512

__device__ __forceinline__ float bflo(uint32_t p){ union{uint32_t u; float f;} v; v.u = p<<16; return v.f; }
__device__ __forceinline__ float bfhi(uint32_t p){ union{uint32_t u; float f;} v; v.u = p & 0xffff0000u; return v.f; }
__device__ __forceinline__ float bf1(u16 x){ union{uint32_t u; float f;} v; v.u = ((uint32_t)x)<<16; return v.f; }
__device__ __forceinline__ u16 f2bf(float f){
  union{float f; uint32_t u;} v; v.f = f;
  uint32_t u = v.u;
  u += 0x7fffu + ((u>>16)&1u);   // round-to-nearest-even
  return (u16)(u>>16);
}

__device__ __forceinline__ void async16(const void* g, void* l){
  __builtin_amdgcn_global_load_lds((const __attribute__((address_space(1))) uint32_t*)g,
                                   (__attribute__((address_space(3))) uint32_t*)l, 16, 0, 0);
}

// -------------------- embedding + positional encoding (bf16 x only) --------------------
__global__ __launch_bounds__(256) void embed_kernel(const int* __restrict__ text,
    const float* __restrict__ emb, const float* __restrict__ pe,
    u16* __restrict__ xb, const int tok0){
  const int gid = blockIdx.x*256 + threadIdx.x;
  const int base = gid*4;
  const int tl = base >> 9;
  const int f  = base & 511;
  const int tg = tl + tok0;
  const int s  = tg & 511;
  const int tok = text[tg];
  const float4 e4 = *(const float4*)(emb + (size_t)tok*FDIM + f);
  const float4 p4 = *(const float4*)(pe  + (size_t)s*FDIM + f);
  ushort4 ob;
  ob.x = f2bf(e4.x + p4.x);
  ob.y = f2bf(e4.y + p4.y);
  ob.z = f2bf(e4.z + p4.z);
  ob.w = f2bf(e4.w + p4.w);
  *(ushort4*)(xb + base) = ob;
}

// -------------------- weight transpose + fp32->bf16: WT[lay][n][k], n: Wq|Wk|Wv|Wf --------------------
__global__ __launch_bounds__(256) void transpose_w(const float* __restrict__ Wq,
    const float* __restrict__ Wk, const float* __restrict__ Wv, const float* __restrict__ Wf,
    u16* __restrict__ WT){
  const int gid = blockIdx.x*256 + threadIdx.x;
  const int n   = gid & 2047;
  const int k8  = (gid>>11) & 63;
  const int lay = gid >> 17;
  const float* src; int col;
  if      (n <  512){ src = Wq; col = n;      }
  else if (n < 1024){ src = Wk; col = n-512;  }
  else if (n < 1536){ src = Wv; col = n-1024; }
  else              { src = Wf; col = n-1536; }
  src += (size_t)lay*FDIM*FDIM;
  u16 vals[8] __attribute__((aligned(16)));
  #pragma unroll
  for (int i=0;i<8;i++) vals[i] = f2bf(src[(size_t)(k8*8+i)*FDIM + col]);
  *(int4*)(WT + ((size_t)lay*2048 + n)*FDIM + k8*8) = *(const int4*)vals;
}

// -------------------- 256x256 ring-4 fragment-pipelined MFMA GEMM (BK=32, 8 waves) ------------------
// Register double-buffered K-loop: while MFMA-ing tile t's fragments (in regs), ds_read tile t+1's.
// Ring-4 LDS slots; stage t+3 during tile t; counted vmcnt(8) (never 0 in steady state).
// Two barriers per tile: mid-tile (after own vmcnt(8) -> all waves' t+1 stage loads landed, so the
// cross-wave-staged rows are readable) and tile-boundary (bounds skew so stage t+4 -> slot t&3 only
// lands after every wave consumed its slot-t reads; all reads of a slot are lgkm-consumed pre-barrier).
template<int MODE>
__global__ __launch_bounds__(512, 2) void gemm256(
    const u16* __restrict__ A, const u16* __restrict__ BT,
    const float* __restrict__ b0, const float* __restrict__ b1, const float* __restrict__ b2,
    const u16* __restrict__ resid, u16* __restrict__ C, const int ldC, const int NB){
  __shared__ __attribute__((aligned(16))) short As[4*256*32];   // 64 KiB
  __shared__ __attribute__((aligned(16))) short Bs[4*256*32];   // 64 KiB
  // T1: bijective XCD swizzle (grids here are multiples of 8)
  const int nwg = gridDim.x;
  const int orig = blockIdx.x;
  const int wg = ((nwg & 7) == 0) ? ((orig & 7)*(nwg >> 3) + (orig >> 3)) : orig;
  const int nblk = wg % NB, mblk = wg / NB;
  const int m0 = mblk << 8, n0 = nblk << 8;
  const int tid = threadIdx.x;
  const int wid = tid >> 6, l = tid & 63;
  const int lm = l & 15, quad = l >> 4;

  // ---- stage source: pre-swizzled per-lane global address; LDS dest stays linear ----
  const int srow = wid*16 + (l >> 2);
  const int sch  = (l & 3) ^ ((l >> 3) & 3);
  const char* Asrc0 = (const char*)A  + ((size_t)(m0 + srow))*1024 + sch*16;
  const char* Asrc1 = Asrc0 + 128*1024;
  const char* Bsrc0 = (const char*)BT + ((size_t)(n0 + srow))*1024 + sch*16;
  const char* Bsrc1 = Bsrc0 + 128*1024;
  char* ldsAw = (char*)As + wid*1024;      // wave-uniform; HW adds lane*16
  char* ldsBw = (char*)Bs + wid*1024;

  f32x4 acc[8][4];
  #pragma unroll
  for (int i=0;i<8;i++)
    #pragma unroll
    for (int j=0;j<4;j++){ f32x4 z = {0.f,0.f,0.f,0.f}; acc[i][j] = z; }

  // ---- swizzled fragment-read bases ----
  const int rsel = quad ^ ((lm >> 1) & 3);
  const int aB = ((wid>>2)*128 + lm)*32 + rsel*8;   // shorts within slot
  const int bB = ((wid&3)*64  + lm)*32 + rsel*8;

  // ---- prologue: stage tiles 0,1,2 ----
  #pragma unroll
  for (int kt=0; kt<3; kt++){
    async16(Asrc0 + kt*64, ldsAw + kt*16384);
    async16(Asrc1 + kt*64, ldsAw + kt*16384 + 8192);
    async16(Bsrc0 + kt*64, ldsBw + kt*16384);
    async16(Bsrc1 + kt*64, ldsBw + kt*16384 + 8192);
  }
  frag8 aC[4], aN[4], bE[4], bO[4];
  asm volatile("s_waitcnt vmcnt(8)" ::: "memory");   // own tile-0 loads done
  __builtin_amdgcn_s_barrier();                       // -> ALL waves' tile-0 loads done
  #pragma unroll
  for (int x=0;x<4;x++){
    aC[x] = *(const frag8*)(As + aB + x*512);
    bE[x] = *(const frag8*)(Bs + bB + x*512);
  }

#define MFMA16(AF, BF, RO) \
  __builtin_amdgcn_s_setprio(1); \
  _Pragma("unroll") \
  for (int mi_=0; mi_<4; mi_++) \
    _Pragma("unroll") \
    for (int nj_=0; nj_<4; nj_++) \
      acc[(RO)+mi_][nj_] = __builtin_amdgcn_mfma_f32_16x16x32_bf16(AF[mi_], BF[nj_], acc[(RO)+mi_][nj_], 0,0,0); \
  __builtin_amdgcn_s_setprio(0);

#define TILE_BODY(T_, BU, BL, DOSTAGE, VMC) { \
  const short* sA_ = As + ((T_)&3)*8192; \
  if (DOSTAGE){ \
    const int s3_ = ((T_)+3)&3; const int off_ = ((T_)+3)*64; \
    async16(Asrc0 + off_, ldsAw + s3_*16384); \
    async16(Asrc1 + off_, ldsAw + s3_*16384 + 8192); \
  } \
  _Pragma("unroll") \
  for (int x_=0;x_<4;x_++) aN[x_] = *(const frag8*)(sA_ + aB + 2048 + x_*512); \
  MFMA16(aC, BU, 0) \
  if (DOSTAGE){ \
    const int s3_ = ((T_)+3)&3; const int off_ = ((T_)+3)*64; \
    async16(Bsrc0 + off_, ldsBw + s3_*16384); \
    async16(Bsrc1 + off_, ldsBw + s3_*16384 + 8192); \
  } \
  asm volatile("s_waitcnt vmcnt(" #VMC ")" ::: "memory"); \
  __builtin_amdgcn_s_barrier(); \
  { const short* sA2_ = As + (((T_)+1)&3)*8192; \
    const short* sB2_ = Bs + (((T_)+1)&3)*8192; \
    _Pragma("unroll") \
    for (int x_=0;x_<4;x_++){ \
      aC[x_] = *(const frag8*)(sA2_ + aB + x_*512); \
      BL[x_] = *(const frag8*)(sB2_ + bB + x_*512); } } \
  MFMA16(aN, BU, 4) \
  __builtin_amdgcn_s_barrier(); \
}

  for (int tp=0; tp<6; ++tp){
    TILE_BODY(2*tp,   bE, bO, 1, 8)
    TILE_BODY(2*tp+1, bO, bE, 1, 8)
  }
  TILE_BODY(12, bE, bO, 1, 8)
  TILE_BODY(13, bO, bE, 0, 4)
  TILE_BODY(14, bE, bO, 0, 0)
  // tile 15 (uses bO; no stage, no read-ahead, no barriers needed after)
  {
    const short* sA_ = As + 3*8192;
    #pragma unroll
    for (int x=0;x<4;x++) aN[x] = *(const frag8*)(sA_ + aB + 2048 + x*512);
    MFMA16(aC, bO, 0)
    MFMA16(aN, bO, 4)
  }
#undef TILE_BODY
#undef MFMA16

  // ---- epilogue: bias (+residual) + bf16 store ----
  float bias[4]; int cols[4];
  #pragma unroll
  for (int nj=0;nj<4;nj++){
    const int c = n0 + (wid&3)*64 + nj*16 + lm;
    cols[nj] = c;
    if (MODE==0) bias[nj] = (c<512 ? b0[c] : (c<1024 ? b1[c-512] : b2[c-1024]));
    else         bias[nj] = b0[c];
  }
  #pragma unroll
  for (int mi=0; mi<8; mi++){
    const int rbase = m0 + (wid>>2)*128 + mi*16 + quad*4;
    #pragma unroll
    for (int r=0;r<4;r++){
      const size_t row = (size_t)(rbase + r);
      #pragma unroll
      for (int nj=0;nj<4;nj++){
        float v = acc[mi][nj][r] + bias[nj];
        if (MODE==1) v += bf1(resid[row*FDIM + cols[nj]]);
        C[row*(size_t)ldC + cols[nj]] = f2bf(v);
      }
    }
  }
}

// -------------------- per-token head-attention + residual(bf16) + LN1 (1 wave = 1 token) --------------------
__global__ __launch_bounds__(256) void attn_ln1(const u16* __restrict__ qkvb,
    const u16* __restrict__ xb, const float* __restrict__ gam, const float* __restrict__ bet,
    u16* __restrict__ y1b){
  __shared__ __attribute__((aligned(16))) u16 sQ[4][1536];
  __shared__ float sWt[4][64];
  const int tid = threadIdx.x, w = tid>>6, l = tid&63;
  const int t = blockIdx.x*4 + w;
  {
    const int4* src = (const int4*)(qkvb + (size_t)t*1536);
    int4* dst = (int4*)(&sQ[w][0]);
    #pragma unroll
    for (int i=0;i<3;i++) dst[i*64 + l] = src[i*64 + l];
  }
  __syncthreads();
  const int h = l>>3, g = l&7;
  const u16* qrow = &sQ[w][h*64];
  const u16* krow = &sQ[w][512 + g*64];
  float sc = 0.f;
  const int dstart = (l&31)*2;
  #pragma unroll
  for (int i=0;i<32;i++){
    const int d = (dstart + 2*i) & 63;
    const uint32_t qp = *(const uint32_t*)(qrow + d);
    const uint32_t kp = *(const uint32_t*)(krow + d);
    sc += bflo(qp)*bflo(kp) + bfhi(qp)*bfhi(kp);
  }
  float mx = sc;
  mx = fmaxf(mx, __shfl_xor(mx,1));
  mx = fmaxf(mx, __shfl_xor(mx,2));
  mx = fmaxf(mx, __shfl_xor(mx,4));
  const float e = __expf(sc - mx);
  float ssum = e;
  ssum += __shfl_xor(ssum,1);
  ssum += __shfl_xor(ssum,2);
  ssum += __shfl_xor(ssum,4);
  sWt[w][l] = e / ssum;
  __syncthreads();
  float wt[8];
  #pragma unroll
  for (int gg=0;gg<8;gg++) wt[gg] = sWt[w][h*8+gg];
  float att[8] = {0,0,0,0,0,0,0,0};
  const int d0 = (l&7)*8;
  #pragma unroll
  for (int gg=0;gg<8;gg++){
    const int4 vv = *(const int4*)(&sQ[w][1024 + gg*64 + d0]);
    const uint32_t* vp = (const uint32_t*)&vv;
    #pragma unroll
    for (int p=0;p<4;p++){
      att[2*p]   += wt[gg]*bflo(vp[p]);
      att[2*p+1] += wt[gg]*bfhi(vp[p]);
    }
  }
  const size_t rb = (size_t)t*FDIM + l*8;
  const int4 xv = *(const int4*)(xb + rb);
  const uint32_t* xp = (const uint32_t*)&xv;
  float y[8]; float s1=0.f, s2=0.f;
  #pragma unroll
  for (int p=0;p<4;p++){
    y[2*p]   = att[2*p]   + bflo(xp[p]);
    y[2*p+1] = att[2*p+1] + bfhi(xp[p]);
  }
  #pragma unroll
  for (int j=0;j<8;j++){ s1 += y[j]; s2 += y[j]*y[j]; }
  #pragma unroll
  for (int off=1; off<64; off<<=1){ s1 += __shfl_xor(s1,off); s2 += __shfl_xor(s2,off); }
  const float mean = s1*(1.f/512.f);
  const float var  = s2*(1.f/512.f) - mean*mean;
  const float rstd = rsqrtf(var + 1e-5f);
  const float4 g0 = *(const float4*)(gam + l*8);
  const float4 g1v = *(const float4*)(gam + l*8 + 4);
  const float4 b0v = *(const float4*)(bet + l*8);
  const float4 b1v = *(const float4*)(bet + l*8 + 4);
  float of[8];
  of[0]=(y[0]-mean)*rstd*g0.x + b0v.x;
  of[1]=(y[1]-mean)*rstd*g0.y + b0v.y;
  of[2]=(y[2]-mean)*rstd*g0.z + b0v.z;
  of[3]=(y[3]-mean)*rstd*g0.w + b0v.w;
  of[4]=(y[4]-mean)*rstd*g1v.x + b1v.x;
  of[5]=(y[5]-mean)*rstd*g1v.y + b1v.y;
  of[6]=(y[6]-mean)*rstd*g1v.z + b1v.z;
  of[7]=(y[7]-mean)*rstd*g1v.w + b1v.w;
  u16 ob[8] __attribute__((aligned(16)));
  #pragma unroll
  for (int j=0;j<8;j++) ob[j] = f2bf(of[j]);
  *(int4*)(y1b + rb) = *(const int4*)ob;
}

// -------------------- LN2 over z (bf16); writes bf16 xb (next layer) or fp32 out --------------------
__global__ __launch_bounds__(256) void ln2_kernel(const u16* __restrict__ z,
    const float* __restrict__ gam, const float* __restrict__ bet,
    u16* __restrict__ xb, float* __restrict__ outp, const int final_){
  const int tid = threadIdx.x, w = tid>>6, l = tid&63;
  const int t = blockIdx.x*4 + w;
  const size_t rb = (size_t)t*FDIM + l*8;
  const int4 zv = *(const int4*)(z + rb);
  const uint32_t* zp = (const uint32_t*)&zv;
  float y[8];
  #pragma unroll
  for (int p=0;p<4;p++){ y[2*p]=bflo(zp[p]); y[2*p+1]=bfhi(zp[p]); }
  float s1=0.f, s2=0.f;
  #pragma unroll
  for (int j=0;j<8;j++){ s1+=y[j]; s2+=y[j]*y[j]; }
  #pragma unroll
  for (int off=1; off<64; off<<=1){ s1 += __shfl_xor(s1,off); s2 += __shfl_xor(s2,off); }
  const float mean = s1*(1.f/512.f);
  const float var  = s2*(1.f/512.f) - mean*mean;
  const float rstd = rsqrtf(var + 1e-5f);
  const float4 g0 = *(const float4*)(gam + l*8);
  const float4 g1v = *(const float4*)(gam + l*8 + 4);
  const float4 b0v = *(const float4*)(bet + l*8);
  const float4 b1v = *(const float4*)(bet + l*8 + 4);
  float of[8];
  of[0]=(y[0]-mean)*rstd*g0.x + b0v.x;
  of[1]=(y[1]-mean)*rstd*g0.y + b0v.y;
  of[2]=(y[2]-mean)*rstd*g0.z + b0v.z;
  of[3]=(y[3]-mean)*rstd*g0.w + b0v.w;
  of[4]=(y[4]-mean)*rstd*g1v.x + b1v.x;
  of[5]=(y[5]-mean)*rstd*g1v.y + b1v.y;
  of[6]=(y[6]-mean)*rstd*g1v.z + b1v.z;
  of[7]=(y[7]-mean)*rstd*g1v.w + b1v.w;
  if (final_){
    float4 o0; o0.x=of[0]; o0.y=of[1]; o0.z=of[2]; o0.w=of[3];
    float4 o1; o1.x=of[4]; o1.y=of[5]; o1.z=of[6]; o1.w=of[7];
    *(float4*)(outp + rb) = o0;
    *(float4*)(outp + rb + 4) = o1;
  } else {
    u16 ob[8] __attribute__((aligned(16)));
    #pragma unroll
    for (int j=0;j<8;j++) ob[j] = f2bf(of[j]);
    *(int4*)(xb + rb) = *(const int4*)ob;
  }
}

extern "C" void kernel_launch(void* const* d_in, const int* in_sizes, int n_in,
                              void* d_out, int out_size, void* d_ws, size_t ws_size,
                              hipStream_t stream){
  const int*   text = (const int*)d_in[0];
  const float* emb = (const float*)d_in[1];
  const float* pe  = (const float*)d_in[2];
  const float* Wq  = (const float*)d_in[3];
  const float* bq  = (const float*)d_in[4];
  const float* Wk  = (const float*)d_in[5];
  const float* bk  = (const float*)d_in[6];
  const float* Wv  = (const float*)d_in[7];
  const float* bv  = (const float*)d_in[8];
  const float* g1  = (const float*)d_in[9];
  const float* be1 = (const float*)d_in[10];
  const float* Wf  = (const float*)d_in[11];
  const float* bf_ = (const float*)d_in[12];
  const float* g2  = (const float*)d_in[13];
  const float* be2 = (const float*)d_in[14];
  float* outp = (float*)d_out;               // reference output dtype = float32

  // ---- layout: WT 12.6 MB + per-token {xb 1024 + y1b 1024 + qkv 3072} = 5120 B
  const size_t wtB = (size_t)6*2048*512*2;
  int T = NTOK;                               // single chunk if ws permits (~173 MB)
  while (T > 2048 && wtB + (size_t)T*5120 > ws_size) T >>= 1;

  char* ws = (char*)d_ws;
  u16*   WT  = (u16*)ws;
  char*  act = ws + wtB;
  u16*   xb  = (u16*)act;                       // T*1024 B
  u16*   y1b = (u16*)(act + (size_t)T*1024);    // T*1024 B
  u16*   qkv = (u16*)(act + (size_t)T*2048);    // T*3072 B
  u16*   zb  = qkv;                             // alias: qkv dead once attn_ln1 ran

  hipLaunchKernelGGL(transpose_w, dim3(3072), dim3(256), 0, stream, Wq, Wk, Wv, Wf, WT);

  const int chunks = NTOK / T;
  for (int c = 0; c < chunks; c++){
    const int tok0 = c*T;
    hipLaunchKernelGGL(embed_kernel, dim3(T/2), dim3(256), 0, stream, text, emb, pe, xb, tok0);
    for (int lay=0; lay<6; lay++){
      const u16* WTl = WT + (size_t)lay*2048*FDIM;
      hipLaunchKernelGGL((gemm256<0>), dim3((T/256)*6), dim3(512), 0, stream,
          xb, WTl, bq + lay*FDIM, bk + lay*FDIM, bv + lay*FDIM, (const u16*)nullptr, qkv, 1536, 6);
      hipLaunchKernelGGL(attn_ln1, dim3(T/4), dim3(256), 0, stream,
          qkv, xb, g1 + lay*FDIM, be1 + lay*FDIM, y1b);
      hipLaunchKernelGGL((gemm256<1>), dim3((T/256)*2), dim3(512), 0, stream,
          y1b, WTl + (size_t)1536*FDIM, bf_ + lay*FDIM, (const float*)nullptr, (const float*)nullptr,
          y1b, zb, 512, 2);
      hipLaunchKernelGGL(ln2_kernel, dim3(T/4), dim3(256), 0, stream,
          zb, g2 + lay*FDIM, be2 + lay*FDIM, xb, outp + (size_t)tok0*FDIM, (lay==5)?1:0);
    }
  }
}